// Round 18
// baseline (766.664 us; speedup 1.0000x reference)
//
#include <hip/hip_runtime.h>

// DecoderLayer (B=16, N1=512, D=1024, H=16, Dk=64, FF=4096)
// Round 18 (from R17 @ 758us; GEMMs pinned at 2-phase ceiling ~853 TF):
//  - T5 s_setprio(1) around attention MFMA clusters (m191: +4-7% on
//    independent-block attention; GEMM variant measured negative -> not added).
//  - k_foldbias2: coalesced fold-bias (32 blocks, lane=consecutive c,
//    4-way k-split + LDS reduce; was column-strided 4KB reads).
// All GEMM cores / attention math / residual stream byte-identical to R17.

typedef __attribute__((ext_vector_type(4))) float          f32x4;
typedef __attribute__((ext_vector_type(8))) short          bf16x8;
typedef __attribute__((ext_vector_type(4))) unsigned short us4;

#define DEV static __device__ __forceinline__

DEV float bf2f(short h) {
  union { unsigned u; float f; } c;
  c.u = ((unsigned)(unsigned short)h) << 16;
  return c.f;
}
DEV unsigned short f2bf(float f) {  // round-to-nearest-even
  union { float f; unsigned u; } c; c.f = f;
  return (unsigned short)((c.u + 0x7fffu + ((c.u >> 16) & 1u)) >> 16);
}

// async global->LDS, 16B per lane; LDS dest is wave-uniform base + lane*16B
DEV void gll16(const unsigned short* g, unsigned short* l) {
  __builtin_amdgcn_global_load_lds((const __attribute__((address_space(1))) void*)g,
                                   (__attribute__((address_space(3))) void*)l,
                                   16, 0, 0);
}

// ---------------- transpose + f32->bf16 convert (+optional row scale) ----------------
__global__ __launch_bounds__(256)
void k_transpose_cvt(const float* __restrict__ src, unsigned short* __restrict__ dst,
                     long long sHi, long long sLo,
                     const float* __restrict__ g, int gStride, int R, int C) {
  __shared__ float tile[32][33];
  const int z = blockIdx.z;
  src += (long long)(z >> 1) * sHi + (long long)(z & 1) * sLo;
  dst += (size_t)z * R * C;
  const int c0 = blockIdx.x * 32, r0 = blockIdx.y * 32;
  const int tx = threadIdx.x, ty = threadIdx.y;
#pragma unroll
  for (int i = 0; i < 32; i += 8)
    tile[ty + i][tx] = src[(size_t)(r0 + ty + i) * C + (c0 + tx)];
  __syncthreads();
  const float gv = g ? g[(size_t)z * gStride + r0 + tx] : 1.f;
#pragma unroll
  for (int i = 0; i < 32; i += 8)
    dst[(size_t)(c0 + ty + i) * R + (r0 + tx)] = f2bf(tile[tx][ty + i] * gv);
}

// ---------------- per-pair 8-matrix transpose (Q'a,Q'b,Ka,Va,Kb,Vb,Oa,Ob) ----------
__global__ __launch_bounds__(256)
void k_transpose_pair(const float* __restrict__ base, unsigned short* __restrict__ wbuf,
                      const float* __restrict__ g) {
  __shared__ float tile[32][33];
  const int z = blockIdx.z;
  const int offs[8] = {0, 4, 1, 2, 5, 6, 3, 7};   // * MS, att_W slot per z
  const float* src = base + (size_t)offs[z] * 1048576;
  unsigned short* dst = wbuf + (size_t)z * 1048576;
  const int c0 = blockIdx.x * 32, r0 = blockIdx.y * 32;
  const int tx = threadIdx.x, ty = threadIdx.y;
#pragma unroll
  for (int i = 0; i < 32; i += 8)
    tile[ty + i][tx] = src[(size_t)(r0 + ty + i) * 1024 + (c0 + tx)];
  __syncthreads();
  const float gv = (z < 2) ? g[z * 1024 + r0 + tx] : 1.f;
#pragma unroll
  for (int i = 0; i < 32; i += 8)
    dst[(size_t)(c0 + ty + i) * 1024 + (r0 + tx)] = f2bf(tile[tx][ty + i] * gv);
}

// ---------------- coalesced folded bias (R18) ----------------
// out[i*1024+c] = sum_k b[i*1024+k]*W[i*4MS + k*1024 + c] + bq[i*4096+c]
// grid 32: blk = i*16 + ctile(64 c). threads: cl=t&63 (consecutive c), kl=t>>6.
__global__ __launch_bounds__(256)
void k_foldbias2(const float* __restrict__ b, const float* __restrict__ W,
                 const float* __restrict__ bq, float* __restrict__ out) {
  __shared__ float red[256];
  const int blk = blockIdx.x;
  const int i = blk >> 4, ct = blk & 15;
  const int t = threadIdx.x, cl = t & 63, kl = t >> 6;
  const int c = ct * 64 + cl;
  const float* Wi = W + (size_t)i * 4 * 1048576;
  const float* bi = b + i * 1024;
  float s = 0.f;
  const int k0 = kl * 256;
#pragma unroll 4
  for (int k = k0; k < k0 + 256; ++k)
    s += bi[k] * Wi[(size_t)k * 1024 + c];
  red[t] = s;
  __syncthreads();
  if (kl == 0) {
    s = red[cl] + red[64 + cl] + red[128 + cl] + red[192 + cl];
    out[i * 1024 + c] = s + bq[(size_t)i * 4096 + c];
  }
}

// ---------------- f32 -> bf16 convert with zero row padding ----------------
__global__ __launch_bounds__(256)
void k_cvt_pad(const float* __restrict__ src, unsigned short* __restrict__ dst, int rows) {
  const int r = blockIdx.x;
  const int c = threadIdx.x * 4;
  us4 o;
  if (r < rows) {
    f32x4 v = *(const f32x4*)(src + (size_t)r * 1024 + c);
    o[0] = f2bf(v[0]); o[1] = f2bf(v[1]); o[2] = f2bf(v[2]); o[3] = f2bf(v[3]);
  } else {
    o[0] = 0; o[1] = 0; o[2] = 0; o[3] = 0;
  }
  *(us4*)(dst + (size_t)r * 1024 + c) = o;
}

__global__ __launch_bounds__(256)
void k_cvt_pad2(const float* __restrict__ src0, const float* __restrict__ src1,
                unsigned short* __restrict__ dst0, unsigned short* __restrict__ dst1,
                int rows) {
  const int r = blockIdx.x, z = blockIdx.y;
  const float* src = z ? src1 : src0;
  unsigned short* dst = z ? dst1 : dst0;
  const int c = threadIdx.x * 4;
  us4 o;
  if (r < rows) {
    f32x4 v = *(const f32x4*)(src + (size_t)r * 1024 + c);
    o[0] = f2bf(v[0]); o[1] = f2bf(v[1]); o[2] = f2bf(v[2]); o[3] = f2bf(v[3]);
  } else {
    o[0] = 0; o[1] = 0; o[2] = 0; o[3] = 0;
  }
  *(us4*)(dst + (size_t)r * 1024 + c) = o;
}

// ---------------- LayerNorm (D=1024) -> bf16 out; input f32 or bf16 ----------------
template <bool AFFINE, bool BF16IN>
__global__ __launch_bounds__(256)
void k_ln(const void* __restrict__ xv, const float* __restrict__ g,
          const float* __restrict__ bb, unsigned short* __restrict__ y) {
  __shared__ float red[8];
  const size_t base = (size_t)blockIdx.x * 1024;
  const int t = threadIdx.x;
  float v[4];
  if constexpr (BF16IN) {
    const us4 u = *(const us4*)((const unsigned short*)xv + base + t * 4);
#pragma unroll
    for (int j = 0; j < 4; ++j) v[j] = bf2f((short)u[j]);
  } else {
    const f32x4 f = *(const f32x4*)((const float*)xv + base + t * 4);
#pragma unroll
    for (int j = 0; j < 4; ++j) v[j] = f[j];
  }
  float s  = v[0] + v[1] + v[2] + v[3];
  float s2 = v[0]*v[0] + v[1]*v[1] + v[2]*v[2] + v[3]*v[3];
#pragma unroll
  for (int m = 32; m >= 1; m >>= 1) { s += __shfl_xor(s, m); s2 += __shfl_xor(s2, m); }
  const int w = t >> 6;
  if ((t & 63) == 0) { red[w] = s; red[4 + w] = s2; }
  __syncthreads();
  s  = red[0] + red[1] + red[2] + red[3];
  s2 = red[4] + red[5] + red[6] + red[7];
  const float mean = s * (1.f / 1024.f);
  const float var  = s2 * (1.f / 1024.f) - mean * mean;
  const float rstd = rsqrtf(var + 1e-5f);
  us4 o;
#pragma unroll
  for (int j = 0; j < 4; ++j) {
    const float zv = (v[j] - mean) * rstd;
    o[j] = f2bf(AFFINE ? zv * g[t * 4 + j] + bb[t * 4 + j] : zv);
  }
  *(us4*)(y + base + t * 4) = o;
}

// ---------------- GEMM core (R9-verified): 128x128 tile, 2-phase dbuf ----------------
template <int MODE, int BK>
DEV void gemm_core(const unsigned short* __restrict__ A,
                   const unsigned short* __restrict__ Bt,
                   const float* __restrict__ bias,
                   void* __restrict__ Cout,
                   const float* __restrict__ res,
                   int N, int K, int bx, int by,
                   unsigned short* sA, unsigned short* sB) {
  const int t = threadIdx.x;
  const int l = t & 63, w = t >> 6;
  const int wr = w >> 1, wc = w & 1;

  constexpr int  LPR = BK / 8;
  constexpr int  RPI = 64 / LPR;
  constexpr int  IPW = 32 / RPI;
  constexpr int  BUF = 128 * BK;
  constexpr bool SWZ = (BK == 64);

  const int glr = l / LPR;
  const int glc = SWZ ? (((l & 7) ^ (l >> 3)) << 3) : ((l % LPR) << 3);
  const unsigned short* gA = A  + (size_t)(by * 128 + w * 32 + glr) * K + glc;
  const unsigned short* gB = Bt + (size_t)(bx * 128 + w * 32 + glr) * K + glc;
  const int wofs = w * 32 * BK;

  const int lr = l & 15;
  const int gq = l >> 4;
  const int xr = SWZ ? (lr & 7) : 0;

  f32x4 acc[4][4];
#pragma unroll
  for (int m = 0; m < 4; ++m)
#pragma unroll
    for (int n = 0; n < 4; ++n) { acc[m][n][0]=0.f; acc[m][n][1]=0.f; acc[m][n][2]=0.f; acc[m][n][3]=0.f; }

  auto stage = [&](int buf, int k0) {
#pragma unroll
    for (int i = 0; i < IPW; ++i) {
      gll16(gA + (size_t)i * RPI * K + k0, sA + buf * BUF + wofs + i * RPI * BK);
      gll16(gB + (size_t)i * RPI * K + k0, sB + buf * BUF + wofs + i * RPI * BK);
    }
  };
  auto compute = [&](int buf) {
#pragma unroll
    for (int ks = 0; ks < BK / 32; ++ks) {
      const int col = (((ks * 4 + gq) ^ xr) << 3);
      const unsigned short* sAr = sA + buf * BUF + (wr * 64 + lr) * BK + col;
      const unsigned short* sBr = sB + buf * BUF + (wc * 64 + lr) * BK + col;
      bf16x8 af[4], bfr[4];
#pragma unroll
      for (int m = 0; m < 4; ++m) af[m]  = *(const bf16x8*)(sAr + m * 16 * BK);
#pragma unroll
      for (int n = 0; n < 4; ++n) bfr[n] = *(const bf16x8*)(sBr + n * 16 * BK);
#pragma unroll
      for (int m = 0; m < 4; ++m)
#pragma unroll
        for (int n = 0; n < 4; ++n)
          acc[m][n] = __builtin_amdgcn_mfma_f32_16x16x32_bf16(af[m], bfr[n], acc[m][n], 0, 0, 0);
    }
  };

  stage(0, 0);
  __syncthreads();
  int cur = 0;
  for (int k0 = BK; k0 < K; k0 += BK) {
    stage(cur ^ 1, k0);
    compute(cur);
    __syncthreads();
    cur ^= 1;
  }
  compute(cur);

  const int rq = (l >> 4) << 2;  // C/D: col = lane&15, row = (lane>>4)*4 + reg
#pragma unroll
  for (int n = 0; n < 4; ++n) {
    const int cg = bx * 128 + wc * 64 + n * 16 + lr;
    const float bv = bias[cg];
#pragma unroll
    for (int m = 0; m < 4; ++m) {
#pragma unroll
      for (int r = 0; r < 4; ++r) {
        const int rg = by * 128 + wr * 64 + m * 16 + rq + r;
        const float v = acc[m][n][r] + bv;
        if constexpr (MODE == 0) {
          ((unsigned short*)Cout)[(size_t)rg * N + cg] = f2bf(v);
        } else if constexpr (MODE == 1) {
          ((unsigned short*)Cout)[(size_t)rg * N + cg] = f2bf(v > 0.f ? v : 0.f);
        } else {
          ((float*)Cout)[(size_t)rg * N + cg] = res[(size_t)rg * N + cg] + v;
        }
      }
    }
  }
}

template <int MODE, int BK>
__global__ __launch_bounds__(256)
void k_gemm(const unsigned short* __restrict__ A,
            const unsigned short* __restrict__ Bt,
            const float* __restrict__ bias,
            void* __restrict__ Cout,
            const float* __restrict__ res,
            int N, int K, int nbx) {
  __shared__ unsigned short sA[2 * 128 * BK];
  __shared__ unsigned short sB[2 * 128 * BK];
  const int nwg = gridDim.x;
  const int q8  = nwg >> 3;
  const int swz = (blockIdx.x & 7) * q8 + (blockIdx.x >> 3);
  gemm_core<MODE, BK>(A, Bt, bias, Cout, res, N, K, swz % nbx, swz / nbx, sA, sB);
}

// ---------------- 8-wave 128x128 BK=64 GEMM (R15-verified): 16 waves/CU ----------------
// MODE 2: f32 res -> bf16 out; MODE 3: bf16 res -> f32 out.
template <int MODE>
__global__ __launch_bounds__(512)
void k_gemm8(const unsigned short* __restrict__ A,
             const unsigned short* __restrict__ Bt,
             const float* __restrict__ bias,
             void* __restrict__ Cout,
             const void* __restrict__ res,
             int N, int K, int nbx) {
  constexpr int BUF = 128 * 64;
  __shared__ unsigned short sA[2 * BUF];
  __shared__ unsigned short sB[2 * BUF];
  const int t = threadIdx.x, l = t & 63, w = t >> 6;
  const int wr = w >> 1, wc = w & 1;
  const int nwg = gridDim.x, q8 = nwg >> 3;
  const int swz = (blockIdx.x & 7) * q8 + (blockIdx.x >> 3);
  const int bx = swz % nbx, by = swz / nbx;

  const int srow = w * 8 + (l >> 3);
  const int scol = ((l & 7) ^ ((l >> 3) & 7)) << 3;
  const unsigned short* gA = A  + (size_t)(by * 128 + srow) * K + scol;
  const unsigned short* gB = Bt + (size_t)(bx * 128 + srow) * K + scol;
  const size_t r64 = (size_t)64 * K;
  const int wofs = w * 8 * 64;

  const int lr = l & 15, gq = l >> 4, xr = lr & 7;

  f32x4 acc[2][4];
#pragma unroll
  for (int m = 0; m < 2; ++m)
#pragma unroll
    for (int n = 0; n < 4; ++n) { acc[m][n][0]=0.f; acc[m][n][1]=0.f; acc[m][n][2]=0.f; acc[m][n][3]=0.f; }

  auto stage = [&](int buf, int k0) {
    gll16(gA + k0,       sA + buf * BUF + wofs);
    gll16(gA + r64 + k0, sA + buf * BUF + wofs + 64 * 64);
    gll16(gB + k0,       sB + buf * BUF + wofs);
    gll16(gB + r64 + k0, sB + buf * BUF + wofs + 64 * 64);
  };
  auto compute = [&](int buf) {
#pragma unroll
    for (int ks = 0; ks < 2; ++ks) {
      const int col = (((ks * 4 + gq) ^ xr) << 3);
      const unsigned short* sAr = sA + buf * BUF + (wr * 32 + lr) * 64 + col;
      const unsigned short* sBr = sB + buf * BUF + (wc * 64 + lr) * 64 + col;
      bf16x8 af[2], bfr[4];
#pragma unroll
      for (int m = 0; m < 2; ++m) af[m]  = *(const bf16x8*)(sAr + m * 16 * 64);
#pragma unroll
      for (int n = 0; n < 4; ++n) bfr[n] = *(const bf16x8*)(sBr + n * 16 * 64);
#pragma unroll
      for (int m = 0; m < 2; ++m)
#pragma unroll
        for (int n = 0; n < 4; ++n)
          acc[m][n] = __builtin_amdgcn_mfma_f32_16x16x32_bf16(af[m], bfr[n], acc[m][n], 0, 0, 0);
    }
  };

  stage(0, 0);
  __syncthreads();
  int cur = 0;
  for (int k0 = 64; k0 < K; k0 += 64) {
    stage(cur ^ 1, k0);
    compute(cur);
    __syncthreads();
    cur ^= 1;
  }
  compute(cur);

  const int rq = (l >> 4) << 2;
#pragma unroll
  for (int n = 0; n < 4; ++n) {
    const int cg = bx * 128 + wc * 64 + n * 16 + lr;
    const float bv = bias[cg];
#pragma unroll
    for (int m = 0; m < 2; ++m) {
#pragma unroll
      for (int r = 0; r < 4; ++r) {
        const int rg = by * 128 + wr * 32 + m * 16 + rq + r;
        const size_t idx = (size_t)rg * N + cg;
        const float v = acc[m][n][r] + bv;
        if constexpr (MODE == 2) {
          ((unsigned short*)Cout)[idx] = f2bf(((const float*)res)[idx] + v);
        } else {
          ((float*)Cout)[idx] =
              bf2f((short)((const unsigned short*)res)[idx]) + v;
        }
      }
    }
  }
}

// ---------------- WIDE GEMM core (R16-verified): 256x128, 8 waves, slot-swizzled ------
template <int MODE>
DEV void gemm_w_core(const unsigned short* __restrict__ A,
                     const unsigned short* __restrict__ Bt,
                     const float* __restrict__ bias,
                     unsigned short* __restrict__ Cout,
                     int N, int K, int bx, int by,
                     unsigned short* sA, unsigned short* sB) {
  constexpr int BUFA = 256 * 32;
  constexpr int BUFB = 128 * 32;
  const int t = threadIdx.x, l = t & 63, w = t >> 6;
  const int wr = w >> 1, wc = w & 1;

  const int glr = l >> 2;
  const int glc = ((l & 3) ^ ((l >> 3) & 3)) << 3;
  const unsigned short* gA = A  + (size_t)(by * 256 + w * 32 + glr) * K + glc;
  const unsigned short* gB = Bt + (size_t)(bx * 128 + w * 16 + glr) * K + glc;
  const size_t r16 = (size_t)16 * K;
  const int wofsA = w * 32 * 32;
  const int wofsB = w * 16 * 32;

  const int lr = l & 15;
  const int lk = (((l >> 4) ^ ((l >> 1) & 3)) << 3);

  f32x4 acc[4][4];
#pragma unroll
  for (int m = 0; m < 4; ++m)
#pragma unroll
    for (int n = 0; n < 4; ++n) { acc[m][n][0]=0.f; acc[m][n][1]=0.f; acc[m][n][2]=0.f; acc[m][n][3]=0.f; }

  auto stage = [&](int buf, int k0) {
    gll16(gA + k0,       sA + buf * BUFA + wofsA);
    gll16(gA + r16 + k0, sA + buf * BUFA + wofsA + 512);
    gll16(gB + k0,       sB + buf * BUFB + wofsB);
  };
  auto compute = [&](int buf) {
    const unsigned short* sAr = sA + buf * BUFA + (wr * 64 + lr) * 32 + lk;
    const unsigned short* sBr = sB + buf * BUFB + (wc * 64 + lr) * 32 + lk;
    bf16x8 af[4], bfr[4];
#pragma unroll
    for (int m = 0; m < 4; ++m) af[m]  = *(const bf16x8*)(sAr + m * 16 * 32);
#pragma unroll
    for (int n = 0; n < 4; ++n) bfr[n] = *(const bf16x8*)(sBr + n * 16 * 32);
#pragma unroll
    for (int m = 0; m < 4; ++m)
#pragma unroll
      for (int n = 0; n < 4; ++n)
        acc[m][n] = __builtin_amdgcn_mfma_f32_16x16x32_bf16(af[m], bfr[n], acc[m][n], 0, 0, 0);
  };

  stage(0, 0);
  __syncthreads();
  int cur = 0;
  for (int k0 = 32; k0 < K; k0 += 32) {
    stage(cur ^ 1, k0);
    compute(cur);
    __syncthreads();
    cur ^= 1;
  }
  compute(cur);

  const int rq = (l >> 4) << 2;
#pragma unroll
  for (int n = 0; n < 4; ++n) {
    const int cg = bx * 128 + wc * 64 + n * 16 + lr;
    const float bv = bias[cg];
#pragma unroll
    for (int m = 0; m < 4; ++m) {
#pragma unroll
      for (int r = 0; r < 4; ++r) {
        const int rg = by * 256 + wr * 64 + m * 16 + rq + r;
        const float v = acc[m][n][r] + bv;
        if constexpr (MODE == 0) {
          Cout[(size_t)rg * N + cg] = f2bf(v);
        } else {
          Cout[(size_t)rg * N + cg] = f2bf(v > 0.f ? v : 0.f);
        }
      }
    }
  }
}

template <int MODE>
__global__ __launch_bounds__(512)
void k_gemm_w(const unsigned short* __restrict__ A,
              const unsigned short* __restrict__ Bt,
              const float* __restrict__ bias,
              unsigned short* __restrict__ Cout,
              int N, int K, int nbx) {
  __shared__ unsigned short sA[2 * 256 * 32];
  __shared__ unsigned short sB[2 * 128 * 32];
  const int nwg = gridDim.x, q8 = nwg >> 3;
  const int swz = (blockIdx.x & 7) * q8 + (blockIdx.x >> 3);
  gemm_w_core<MODE>(A, Bt, bias, Cout, N, K, swz % nbx, swz / nbx, sA, sB);
}

__global__ __launch_bounds__(512)
void k_gemm2_w(const unsigned short* __restrict__ A0, const unsigned short* __restrict__ B0,
               const float* __restrict__ b0, unsigned short* __restrict__ C0,
               const unsigned short* __restrict__ A1, const unsigned short* __restrict__ B1,
               const float* __restrict__ b1, unsigned short* __restrict__ C1,
               int N, int K, int nbx, int nblk0) {
  __shared__ unsigned short sA[2 * 256 * 32];
  __shared__ unsigned short sB[2 * 128 * 32];
  const int nwg = gridDim.x, q8 = nwg >> 3;
  int swz = (blockIdx.x & 7) * q8 + (blockIdx.x >> 3);
  const unsigned short* A; const unsigned short* Bt; const float* bias; unsigned short* C;
  if (swz < nblk0) { A = A0; Bt = B0; bias = b0; C = C0; }
  else { swz -= nblk0; A = A1; Bt = B1; bias = b1; C = C1; }
  gemm_w_core<0>(A, Bt, bias, C, N, K, swz % nbx, swz / nbx, sA, sB);
}

__global__ __launch_bounds__(512)
void k_gemm3_w(const unsigned short* __restrict__ A0, const unsigned short* __restrict__ B0,
               const float* __restrict__ b0, unsigned short* __restrict__ C0,
               const unsigned short* __restrict__ A1, const unsigned short* __restrict__ B1,
               const float* __restrict__ b1, unsigned short* __restrict__ C1,
               const unsigned short* __restrict__ A2, const unsigned short* __restrict__ B2,
               const float* __restrict__ b2, unsigned short* __restrict__ C2,
               int N, int K, int nbx, int nblk0, int nblk1) {
  __shared__ unsigned short sA[2 * 256 * 32];
  __shared__ unsigned short sB[2 * 128 * 32];
  const int nwg = gridDim.x, q8 = nwg >> 3;
  int swz = (blockIdx.x & 7) * q8 + (blockIdx.x >> 3);
  const unsigned short* A; const unsigned short* Bt; const float* bias; unsigned short* C;
  if (swz < nblk0) { A = A0; Bt = B0; bias = b0; C = C0; }
  else if (swz < nblk0 + nblk1) { swz -= nblk0; A = A1; Bt = B1; bias = b1; C = C1; }
  else { swz -= nblk0 + nblk1; A = A2; Bt = B2; bias = b2; C = C2; }
  gemm_w_core<0>(A, Bt, bias, C, N, K, swz % nbx, swz / nbx, sA, sB);
}

// 3-group 128^2 GEMM (tier-1 visual fallback)
__global__ __launch_bounds__(256)
void k_gemm3(const unsigned short* __restrict__ A0, const unsigned short* __restrict__ B0,
             const float* __restrict__ b0, unsigned short* __restrict__ C0,
             const unsigned short* __restrict__ A1, const unsigned short* __restrict__ B1,
             const float* __restrict__ b1, unsigned short* __restrict__ C1,
             const unsigned short* __restrict__ A2, const unsigned short* __restrict__ B2,
             const float* __restrict__ b2, unsigned short* __restrict__ C2,
             int N, int K, int nbx, int nblk0, int nblk1) {
  __shared__ unsigned short sA[2 * 128 * 32];
  __shared__ unsigned short sB[2 * 128 * 32];
  const int nwg = gridDim.x;
  const int q8  = nwg >> 3;
  int swz = (blockIdx.x & 7) * q8 + (blockIdx.x >> 3);
  const unsigned short* A; const unsigned short* Bt; const float* bias; unsigned short* C;
  if (swz < nblk0) { A = A0; Bt = B0; bias = b0; C = C0; }
  else if (swz < nblk0 + nblk1) { swz -= nblk0; A = A1; Bt = B1; bias = b1; C = C1; }
  else { swz -= nblk0 + nblk1; A = A2; Bt = B2; bias = b2; C = C2; }
  gemm_core<0, 32>(A, Bt, bias, C, nullptr, N, K, swz % nbx, swz / nbx, sA, sB);
}

// ---------------- MFMA flash attention (R14-verified + R18 setprio) ----------------
template <bool CAUSAL>
__global__ __launch_bounds__(512)
void k_attn_mfma(const unsigned short* __restrict__ Q,
                 const unsigned short* __restrict__ Kb,
                 const unsigned short* __restrict__ Vb,
                 unsigned short* __restrict__ O,
                 int kvlen, int qs, int ks) {
  __shared__ __align__(16) unsigned short sK [64 * 64];
  __shared__ __align__(16) unsigned short sVt[64 * 64];
  __shared__ __align__(16) unsigned short sP [8][16 * 64];
  const int b = blockIdx.z, h = blockIdx.y, q0 = blockIdx.x * 128;
  const int t = threadIdx.x, w = t >> 6, l = t & 63;
  const int cc = l & 15, g = l >> 4;
  const int gk = g << 3;

  const unsigned short* qg =
      Q + (size_t)(b * 512 + q0 + w * 16 + cc) * qs + h * 64 + gk;
  bf16x8 qf[2];
  qf[0] = *(const bf16x8*)(qg);
  qf[1] = *(const bf16x8*)(qg + 32);

  f32x4 accO[4];
#pragma unroll
  for (int n = 0; n < 4; ++n) { accO[n][0]=0.f; accO[n][1]=0.f; accO[n][2]=0.f; accO[n][3]=0.f; }
  float om[4], ls[4];
#pragma unroll
  for (int r = 0; r < 4; ++r) { om[r] = -1e30f; ls[r] = 0.f; }

  const int krow = w * 8 + (l >> 3);
  const int kcol = ((l & 7) ^ ((l >> 3) & 7)) << 3;
  const size_t kstg = (size_t)(b * kvlen + krow) * ks + h * 64 + kcol;
  unsigned short* kdst = sK + w * 8 * 64;

  const int vrow = t >> 3;
  const int vd0  = (t & 7) << 3;
  const size_t vstg = (size_t)(b * kvlen + vrow) * ks + h * 64 + vd0;

  const int kvmax = CAUSAL ? (q0 + 128) : kvlen;
  for (int c0 = 0; c0 < kvmax; c0 += 64) {
    __syncthreads();
    gll16(Kb + kstg + (size_t)c0 * ks, kdst);
    const bf16x8 vv = *(const bf16x8*)(Vb + vstg + (size_t)c0 * ks);
#pragma unroll
    for (int i = 0; i < 8; ++i) {
      const int j = (i + (t & 7)) & 7;
      sVt[(vd0 + j) * 64 + (vrow ^ (j << 3))] = (unsigned short)vv[j];
    }
    __syncthreads();

    // ---- S = Q.K^T (T5: setprio around MFMA cluster) ----
    f32x4 S[4];
#pragma unroll
    for (int n = 0; n < 4; ++n) { S[n][0]=0.f; S[n][1]=0.f; S[n][2]=0.f; S[n][3]=0.f; }
    __builtin_amdgcn_s_setprio(1);
#pragma unroll
    for (int n = 0; n < 4; ++n) {
      const int kvr = (n * 16 + cc) * 64;
      const int sxk = (cc & 7) << 3;
#pragma unroll
      for (int ks2 = 0; ks2 < 2; ++ks2) {
        const bf16x8 kf = *(const bf16x8*)(sK + kvr + ((ks2 * 32 + gk) ^ sxk));
        S[n] = __builtin_amdgcn_mfma_f32_16x16x32_bf16(qf[ks2], kf, S[n], 0, 0, 0);
      }
    }
    __builtin_amdgcn_s_setprio(0);

    float cm[4];
#pragma unroll
    for (int r = 0; r < 4; ++r) cm[r] = -1e30f;
#pragma unroll
    for (int n = 0; n < 4; ++n) {
      const int kvg = c0 + n * 16 + cc;
#pragma unroll
      for (int r = 0; r < 4; ++r) {
        const int qrow = q0 + w * 16 + g * 4 + r;
        const bool valid = (kvg < kvlen) && (!CAUSAL || kvg <= qrow);
        const float sv = valid ? S[n][r] * 0.125f : -1e30f;
        S[n][r] = sv;
        cm[r] = fmaxf(cm[r], sv);
      }
    }
#pragma unroll
    for (int m2 = 1; m2 <= 8; m2 <<= 1)
#pragma unroll
      for (int r = 0; r < 4; ++r) cm[r] = fmaxf(cm[r], __shfl_xor(cm[r], m2));

    float sc4[4], ps[4];
#pragma unroll
    for (int r = 0; r < 4; ++r) {
      const float mn = fmaxf(om[r], cm[r]);
      sc4[r] = __expf(om[r] - mn);
      om[r] = mn;
      ps[r] = 0.f;
    }
#pragma unroll
    for (int n = 0; n < 4; ++n) {
#pragma unroll
      for (int r = 0; r < 4; ++r) {
        const float pv = __expf(S[n][r] - om[r]);
        ps[r] += pv;
        const int q = g * 4 + r;
        sP[w][q * 64 + ((n * 16 + cc) ^ ((q & 7) << 3))] = f2bf(pv);
      }
    }
#pragma unroll
    for (int m2 = 1; m2 <= 8; m2 <<= 1)
#pragma unroll
      for (int r = 0; r < 4; ++r) ps[r] += __shfl_xor(ps[r], m2);
#pragma unroll
    for (int r = 0; r < 4; ++r) ls[r] = ls[r] * sc4[r] + ps[r];
#pragma unroll
    for (int n = 0; n < 4; ++n)
#pragma unroll
      for (int r = 0; r < 4; ++r) accO[n][r] *= sc4[r];

    // ---- O += P.V (T5: setprio around MFMA cluster) ----
    const int pxk = (cc & 7) << 3;
    __builtin_amdgcn_s_setprio(1);
#pragma unroll
    for (int ks2 = 0; ks2 < 2; ++ks2) {
      const bf16x8 pf = *(const bf16x8*)(&sP[w][cc * 64 + ((ks2 * 32 + gk) ^ pxk)]);
#pragma unroll
      for (int n = 0; n < 4; ++n) {
        const int d = n * 16 + cc;
        const bf16x8 vf = *(const bf16x8*)(sVt + d * 64 + ((ks2 * 32 + gk) ^ ((d & 7) << 3)));
        accO[n] = __builtin_amdgcn_mfma_f32_16x16x32_bf16(pf, vf, accO[n], 0, 0, 0);
      }
    }
    __builtin_amdgcn_s_setprio(0);
  }

#pragma unroll
  for (int r = 0; r < 4; ++r) {
    const float inv = 1.f / ls[r];
    const size_t ob = ((size_t)(b * 512 + q0 + w * 16 + g * 4 + r) << 10) + h * 64;
#pragma unroll
    for (int n = 0; n < 4; ++n)
      O[ob + n * 16 + cc] = f2bf(accO[n][r] * inv);
  }
}

// ---------------- fuse gate, phase 1 (c is bf16) ----------------
__global__ __launch_bounds__(256)
void k_pair1(const unsigned short* __restrict__ c, const unsigned short* __restrict__ p1,
             const unsigned short* __restrict__ p2, unsigned short* __restrict__ acc) {
  __shared__ float red[8];
  const size_t base = (size_t)blockIdx.x * 1024;
  const int t = threadIdx.x;
  const us4 uc = *(const us4*)(c + base + t * 4);
  const us4 u1 = *(const us4*)(p1 + base + t * 4);
  const us4 u2 = *(const us4*)(p2 + base + t * 4);
  float cv[4], f1v[4], f2v[4];
  float d1 = 0.f, d2 = 0.f;
#pragma unroll
  for (int j = 0; j < 4; ++j) {
    cv[j] = bf2f((short)uc[j]);
    f1v[j] = bf2f((short)u1[j]); f2v[j] = bf2f((short)u2[j]);
    d1 += cv[j] * f1v[j]; d2 += cv[j] * f2v[j];
  }
#pragma unroll
  for (int m = 32; m >= 1; m >>= 1) { d1 += __shfl_xor(d1, m); d2 += __shfl_xor(d2, m); }
  const int w = t >> 6;
  if ((t & 63) == 0) { red[w] = d1; red[4 + w] = d2; }
  __syncthreads();
  d1 = red[0] + red[1] + red[2] + red[3];
  d2 = red[4] + red[5] + red[6] + red[7];
  const float mx = fmaxf(d1, d2);
  const float e1 = __expf(d1 - mx), e2 = __expf(d2 - mx);
  const float w1 = e1 / (e1 + e2), w2 = e2 / (e1 + e2);
  us4 o;
#pragma unroll
  for (int j = 0; j < 4; ++j) o[j] = f2bf(0.5f * (w1 * f1v[j] + w2 * f2v[j]));
  *(us4*)(acc + base + t * 4) = o;
}

// ---------------- fuse gate phase 2 + final LayerNorm (c is bf16, in/out) --------------
__global__ __launch_bounds__(256)
void k_pair2ln(unsigned short* __restrict__ c, const unsigned short* __restrict__ p1,
               const unsigned short* __restrict__ p2, const unsigned short* __restrict__ acc,
               const float* __restrict__ g, const float* __restrict__ bb,
               unsigned short* __restrict__ y) {
  __shared__ float red[16];
  const size_t base = (size_t)blockIdx.x * 1024;
  const int t = threadIdx.x;
  const int w = t >> 6;
  const us4 uc = *(const us4*)(c + base + t * 4);
  const us4 u1 = *(const us4*)(p1 + base + t * 4);
  const us4 u2 = *(const us4*)(p2 + base + t * 4);
  const us4 ua = *(const us4*)(acc + base + t * 4);
  float cv[4], f1v[4], f2v[4];
  float d1 = 0.f, d2 = 0.f;
#pragma unroll
  for (int j = 0; j < 4; ++j) {
    cv[j] = bf2f((short)uc[j]);
    f1v[j] = bf2f((short)u1[j]); f2v[j] = bf2f((short)u2[j]);
    d1 += cv[j] * f1v[j]; d2 += cv[j] * f2v[j];
  }
#pragma unroll
  for (int m = 32; m >= 1; m >>= 1) { d1 += __shfl_xor(d1, m); d2 += __shfl_xor(d2, m); }
  if ((t & 63) == 0) { red[w] = d1; red[4 + w] = d2; }
  __syncthreads();
  d1 = red[0] + red[1] + red[2] + red[3];
  d2 = red[4] + red[5] + red[6] + red[7];
  const float mx = fmaxf(d1, d2);
  const float e1 = __expf(d1 - mx), e2 = __expf(d2 - mx);
  const float w1 = e1 / (e1 + e2), w2 = e2 / (e1 + e2);
  f32x4 o;
  us4 oc;
  float s = 0.f, s2 = 0.f;
#pragma unroll
  for (int j = 0; j < 4; ++j) {
    o[j] = cv[j] + bf2f((short)ua[j]) + 0.5f * (w1 * f1v[j] + w2 * f2v[j]);
    oc[j] = f2bf(o[j]);
    s += o[j]; s2 += o[j] * o[j];
  }
  *(us4*)(c + base + t * 4) = oc;
#pragma unroll
  for (int m = 32; m >= 1; m >>= 1) { s += __shfl_xor(s, m); s2 += __shfl_xor(s2, m); }
  if ((t & 63) == 0) { red[8 + w] = s; red[12 + w] = s2; }
  __syncthreads();
  s  = red[8]  + red[9]  + red[10] + red[11];
  s2 = red[12] + red[13] + red[14] + red[15];
  const float mean = s * (1.f / 1024.f);
  const float var  = s2 * (1.f / 1024.f) - mean * mean;
  const float rstd = rsqrtf(var + 1e-5f);
  us4 yo;
#pragma unroll
  for (int j = 0; j < 4; ++j)
    yo[j] = f2bf((o[j] - mean) * rstd * g[t * 4 + j] + bb[t * 4 + j]);
  *(us4*)(y + base + t * 4) = yo;
}

// ---------------- host ----------------
extern "C" void kernel_launch(void* const* d_in, const int* in_sizes, int n_in,
                              void* d_out, int out_size, void* d_ws, size_t ws_size,
                              hipStream_t stream) {
  (void)in_sizes; (void)n_in; (void)out_size;
  const float* captions      = (const float*)d_in[0];
  const float* cpt_words     = (const float*)d_in[1];
  const float* senti_words   = (const float*)d_in[2];
  const float* region_feats  = (const float*)d_in[3];
  const float* spatial_feats = (const float*)d_in[4];
  const float* att_W  = (const float*)d_in[5];
  const float* att_b  = (const float*)d_in[6];
  const float* ffn_W1 = (const float*)d_in[7];
  const float* ffn_b1 = (const float*)d_in[8];
  const float* ffn_W2 = (const float*)d_in[9];
  const float* ffn_b2 = (const float*)d_in[10];
  const float* ln_g   = (const float*)d_in[11];
  const float* ln_b   = (const float*)d_in[12];
  // d_in[13] seq_masks: tril by construction -> causal handled analytically.

  const bool m2 = ws_size >= (size_t)193500000;
  const bool m1 = m2 || ws_size >= (size_t)191000000;
  const int  RPV = m2 ? 3328 : 3200;

  char* ws = (char*)d_ws;
  size_t off = 0;
  auto alloc = [&](size_t bytes) {
    char* p = ws + off;
    off += (bytes + 255) & ~(size_t)255;
    return p;
  };
  const size_t M8 = (size_t)8 * 1024 * 1024;
  unsigned short* hbuf = (unsigned short*)alloc(M8 * 2);
  unsigned short* qx   = (unsigned short*)alloc(M8 * 2 * 4);
  unsigned short* c1   = (unsigned short*)alloc(M8 * 2);   // residual, bf16
  unsigned short* uni  = (unsigned short*)alloc(M8 * 2);
  unsigned short* wbuf = (unsigned short*)alloc(M8 * 2);
  unsigned short* padbA = (unsigned short*)alloc((size_t)RPV * 1024 * 2);
  unsigned short* padbB = m1 ? (unsigned short*)alloc((size_t)RPV * 1024 * 2) : padbA;
  unsigned short* kvbA  = (unsigned short*)alloc((size_t)RPV * 2048 * 2);
  unsigned short* kvbB  = m1 ? (unsigned short*)alloc((size_t)RPV * 2048 * 2) : kvbA;
  float*          qbs  = (float*)alloc(2048 * 4);

  const long long MSL = 1048576;
  const size_t    MSE = 1048576;
  unsigned short* accb = uni;
  unsigned short* wF1t = uni;
  unsigned short* wF2t = uni + (size_t)4096 * 1024;

  const dim3 tb32(32, 8);
  const dim3 gAttn(4, 16, 16);       // QBLK=128

  // ================= self attention (causal) =================
  k_transpose_cvt<<<dim3(32, 32, 4), tb32, 0, stream>>>(att_W, wbuf, 2 * MSL, MSL,
                                                        nullptr, 0, 1024, 1024);
  k_ln<true, false><<<8192, 256, 0, stream>>>(captions, ln_g, ln_b, hbuf);
  k_gemm_w<0><<<768, 512, 0, stream>>>(hbuf, wbuf, att_b, qx, 3072, 1024, 24);
  k_attn_mfma<true><<<gAttn, 512, 0, stream>>>(qx, qx + 1024, qx + 2048,
                                               qx + 3 * M8, 512, 3072, 3072);
  k_gemm8<2><<<512, 512, 0, stream>>>(qx + 3 * M8, wbuf + 3 * MSE, att_b + 3 * 1024,
                                      c1, captions, 1024, 1024, 8);

  // ================= branches (paired), folded LN =================
  k_ln<false, true><<<8192, 256, 0, stream>>>(c1, nullptr, nullptr, hbuf);

  auto branch_pair = [&](int bi0, int Rp, int valid, bool wideKV,
                         const float* wrd0, const float* wrd1, int phase) {
    k_transpose_pair<<<dim3(32, 32, 8), tb32, 0, stream>>>(
        att_W + (size_t)bi0 * 4 * MSE, wbuf, ln_g + (size_t)bi0 * 1024);
    k_foldbias2<<<32, 256, 0, stream>>>(ln_b + (size_t)bi0 * 1024,
                                        att_W + (size_t)bi0 * 4 * MSE,
                                        att_b + (size_t)bi0 * 4 * 1024, qbs);
    const int nrows = valid * 16;
    const float* bKa = att_b + ((size_t)bi0 * 4 + 1) * 1024;
    const float* bKb = att_b + ((size_t)(bi0 + 1) * 4 + 1) * 1024;

    if (m1) {
      k_cvt_pad2<<<dim3(Rp, 2), 256, 0, stream>>>(wrd0, wrd1, padbA, padbB, nrows);
      if (wideKV) {
        const int kvw = (Rp / 256) * 16;
        k_gemm3_w<<<512 + 2 * kvw, 512, 0, stream>>>(
            hbuf, wbuf, qbs, qx,
            padbA, wbuf + 2 * MSE, bKa, kvbA,
            padbB, wbuf + 4 * MSE, bKb, kvbB,
            2048, 1024, 16, 512, kvw);
      } else {
        const int kvblk = (Rp / 128) * 16;
        k_gemm3<<<1024 + 2 * kvblk, 256, 0, stream>>>(
            hbuf, wbuf, qbs, qx,
            padbA, wbuf + 2 * MSE, bKa, kvbA,
            padbB, wbuf + 4 * MSE, bKb, kvbB,
            2048, 1024, 16, 1024, kvblk);
      }
      k_attn_mfma<false><<<gAttn, 512, 0, stream>>>(
          qx, kvbA, kvbA + 1024, qx + 2 * M8, valid, 2048, 2048);
      k_attn_mfma<false><<<gAttn, 512, 0, stream>>>(
          qx + 1024, kvbB, kvbB + 1024, qx + 3 * M8, valid, 2048, 2048);
    } else {
      const int kvblk = (Rp / 128) * 16;
      k_gemm<0, 32><<<1024, 256, 0, stream>>>(hbuf, wbuf, qbs, qx, nullptr,
                                              2048, 1024, 16);
      k_cvt_pad<<<Rp, 256, 0, stream>>>(wrd0, padbA, nrows);
      k_gemm<0, 32><<<kvblk, 256, 0, stream>>>(padbA, wbuf + 2 * MSE, bKa,
                                               kvbA, nullptr, 2048, 1024, 16);
      k_attn_mfma<false><<<gAttn, 512, 0, stream>>>(
          qx, kvbA, kvbA + 1024, qx + 2 * M8, valid, 2048, 2048);
      k_cvt_pad<<<Rp, 256, 0, stream>>>(wrd1, padbA, nrows);
      k_gemm<0, 32><<<kvblk, 256, 0, stream>>>(padbA, wbuf + 4 * MSE, bKb,
                                               kvbA, nullptr, 2048, 1024, 16);
      k_attn_mfma<false><<<gAttn, 512, 0, stream>>>(
          qx + 1024, kvbA, kvbA + 1024, qx + 3 * M8, valid, 2048, 2048);
    }
    k_gemm2_w<<<512, 512, 0, stream>>>(
        qx + 2 * M8, wbuf + 6 * MSE, att_b + ((size_t)bi0 * 4 + 3) * 1024, qx,
        qx + 3 * M8, wbuf + 7 * MSE, att_b + ((size_t)(bi0 + 1) * 4 + 3) * 1024,
        qx + M8, 1024, 1024, 8, 256);
    if (phase == 1) {
      k_pair1<<<8192, 256, 0, stream>>>(c1, qx, qx + M8, accb);
    } else {
      k_pair2ln<<<8192, 256, 0, stream>>>(c1, qx, qx + M8, accb,
                                          ln_g + 5 * 1024, ln_b + 5 * 1024, hbuf);
    }
  };

  branch_pair(1, 512, 25,  m1, cpt_words,    senti_words,   1);  // semantic
  branch_pair(3, RPV, 196, m2, region_feats, spatial_feats, 2);  // visual

  // ================= FFN (LN fused into k_pair2ln) =================
  k_transpose_cvt<<<dim3(128, 32, 1), tb32, 0, stream>>>(ffn_W1, wF1t, 0, 0,
                                                         nullptr, 0, 1024, 4096);
  k_transpose_cvt<<<dim3(32, 128, 1), tb32, 0, stream>>>(ffn_W2, wF2t, 0, 0,
                                                         nullptr, 0, 4096, 1024);
  k_gemm_w<1><<<1024, 512, 0, stream>>>(hbuf, wF1t, ffn_b1, qx, 4096, 1024, 32);
  k_gemm8<3><<<512, 512, 0, stream>>>(qx, wF2t, ffn_b2, (float*)d_out, c1,
                                      1024, 4096, 8);
}

// Round 19
// 765.056 us; speedup vs baseline: 1.0021x; 1.0021x over previous
//
#include <hip/hip_runtime.h>

// DecoderLayer (B=16, N1=512, D=1024, H=16, Dk=64, FF=4096)
// Round 18 (from R17 @ 758us; GEMMs pinned at 2-phase ceiling ~853 TF):
//  - T5 s_setprio(1) around attention MFMA clusters (m191: +4-7% on
//    independent-block attention; GEMM variant measured negative -> not added).
//  - k_foldbias2: coalesced fold-bias (32 blocks, lane=consecutive c,
//    4-way k-split + LDS reduce; was column-strided 4KB reads).
// All GEMM cores / attention math / residual stream byte-identical to R17.

typedef __attribute__((ext_vector_type(4))) float          f32x4;
typedef __attribute__((ext_vector_type(8))) short          bf16x8;
typedef __attribute__((ext_vector_type(4))) unsigned short us4;

#define DEV static __device__ __forceinline__

DEV float bf2f(short h) {
  union { unsigned u; float f; } c;
  c.u = ((unsigned)(unsigned short)h) << 16;
  return c.f;
}
DEV unsigned short f2bf(float f) {  // round-to-nearest-even
  union { float f; unsigned u; } c; c.f = f;
  return (unsigned short)((c.u + 0x7fffu + ((c.u >> 16) & 1u)) >> 16);
}

// async global->LDS, 16B per lane; LDS dest is wave-uniform base + lane*16B
DEV void gll16(const unsigned short* g, unsigned short* l) {
  __builtin_amdgcn_global_load_lds((const __attribute__((address_space(1))) void*)g,
                                   (__attribute__((address_space(3))) void*)l,
                                   16, 0, 0);
}

// ---------------- transpose + f32->bf16 convert (+optional row scale) ----------------
__global__ __launch_bounds__(256)
void k_transpose_cvt(const float* __restrict__ src, unsigned short* __restrict__ dst,
                     long long sHi, long long sLo,
                     const float* __restrict__ g, int gStride, int R, int C) {
  __shared__ float tile[32][33];
  const int z = blockIdx.z;
  src += (long long)(z >> 1) * sHi + (long long)(z & 1) * sLo;
  dst += (size_t)z * R * C;
  const int c0 = blockIdx.x * 32, r0 = blockIdx.y * 32;
  const int tx = threadIdx.x, ty = threadIdx.y;
#pragma unroll
  for (int i = 0; i < 32; i += 8)
    tile[ty + i][tx] = src[(size_t)(r0 + ty + i) * C + (c0 + tx)];
  __syncthreads();
  const float gv = g ? g[(size_t)z * gStride + r0 + tx] : 1.f;
#pragma unroll
  for (int i = 0; i < 32; i += 8)
    dst[(size_t)(c0 + ty + i) * R + (r0 + tx)] = f2bf(tile[tx][ty + i] * gv);
}

// ---------------- per-pair 8-matrix transpose (Q'a,Q'b,Ka,Va,Kb,Vb,Oa,Ob) ----------
__global__ __launch_bounds__(256)
void k_transpose_pair(const float* __restrict__ base, unsigned short* __restrict__ wbuf,
                      const float* __restrict__ g) {
  __shared__ float tile[32][33];
  const int z = blockIdx.z;
  const int offs[8] = {0, 4, 1, 2, 5, 6, 3, 7};   // * MS, att_W slot per z
  const float* src = base + (size_t)offs[z] * 1048576;
  unsigned short* dst = wbuf + (size_t)z * 1048576;
  const int c0 = blockIdx.x * 32, r0 = blockIdx.y * 32;
  const int tx = threadIdx.x, ty = threadIdx.y;
#pragma unroll
  for (int i = 0; i < 32; i += 8)
    tile[ty + i][tx] = src[(size_t)(r0 + ty + i) * 1024 + (c0 + tx)];
  __syncthreads();
  const float gv = (z < 2) ? g[z * 1024 + r0 + tx] : 1.f;
#pragma unroll
  for (int i = 0; i < 32; i += 8)
    dst[(size_t)(c0 + ty + i) * 1024 + (r0 + tx)] = f2bf(tile[tx][ty + i] * gv);
}

// ---------------- coalesced folded bias (R18) ----------------
// out[i*1024+c] = sum_k b[i*1024+k]*W[i*4MS + k*1024 + c] + bq[i*4096+c]
// grid 32: blk = i*16 + ctile(64 c). threads: cl=t&63 (consecutive c), kl=t>>6.
__global__ __launch_bounds__(256)
void k_foldbias2(const float* __restrict__ b, const float* __restrict__ W,
                 const float* __restrict__ bq, float* __restrict__ out) {
  __shared__ float red[256];
  const int blk = blockIdx.x;
  const int i = blk >> 4, ct = blk & 15;
  const int t = threadIdx.x, cl = t & 63, kl = t >> 6;
  const int c = ct * 64 + cl;
  const float* Wi = W + (size_t)i * 4 * 1048576;
  const float* bi = b + i * 1024;
  float s = 0.f;
  const int k0 = kl * 256;
#pragma unroll 4
  for (int k = k0; k < k0 + 256; ++k)
    s += bi[k] * Wi[(size_t)k * 1024 + c];
  red[t] = s;
  __syncthreads();
  if (kl == 0) {
    s = red[cl] + red[64 + cl] + red[128 + cl] + red[192 + cl];
    out[i * 1024 + c] = s + bq[(size_t)i * 4096 + c];
  }
}

// ---------------- f32 -> bf16 convert with zero row padding ----------------
__global__ __launch_bounds__(256)
void k_cvt_pad(const float* __restrict__ src, unsigned short* __restrict__ dst, int rows) {
  const int r = blockIdx.x;
  const int c = threadIdx.x * 4;
  us4 o;
  if (r < rows) {
    f32x4 v = *(const f32x4*)(src + (size_t)r * 1024 + c);
    o[0] = f2bf(v[0]); o[1] = f2bf(v[1]); o[2] = f2bf(v[2]); o[3] = f2bf(v[3]);
  } else {
    o[0] = 0; o[1] = 0; o[2] = 0; o[3] = 0;
  }
  *(us4*)(dst + (size_t)r * 1024 + c) = o;
}

__global__ __launch_bounds__(256)
void k_cvt_pad2(const float* __restrict__ src0, const float* __restrict__ src1,
                unsigned short* __restrict__ dst0, unsigned short* __restrict__ dst1,
                int rows) {
  const int r = blockIdx.x, z = blockIdx.y;
  const float* src = z ? src1 : src0;
  unsigned short* dst = z ? dst1 : dst0;
  const int c = threadIdx.x * 4;
  us4 o;
  if (r < rows) {
    f32x4 v = *(const f32x4*)(src + (size_t)r * 1024 + c);
    o[0] = f2bf(v[0]); o[1] = f2bf(v[1]); o[2] = f2bf(v[2]); o[3] = f2bf(v[3]);
  } else {
    o[0] = 0; o[1] = 0; o[2] = 0; o[3] = 0;
  }
  *(us4*)(dst + (size_t)r * 1024 + c) = o;
}

// ---------------- LayerNorm (D=1024) -> bf16 out; input f32 or bf16 ----------------
template <bool AFFINE, bool BF16IN>
__global__ __launch_bounds__(256)
void k_ln(const void* __restrict__ xv, const float* __restrict__ g,
          const float* __restrict__ bb, unsigned short* __restrict__ y) {
  __shared__ float red[8];
  const size_t base = (size_t)blockIdx.x * 1024;
  const int t = threadIdx.x;
  float v[4];
  if constexpr (BF16IN) {
    const us4 u = *(const us4*)((const unsigned short*)xv + base + t * 4);
#pragma unroll
    for (int j = 0; j < 4; ++j) v[j] = bf2f((short)u[j]);
  } else {
    const f32x4 f = *(const f32x4*)((const float*)xv + base + t * 4);
#pragma unroll
    for (int j = 0; j < 4; ++j) v[j] = f[j];
  }
  float s  = v[0] + v[1] + v[2] + v[3];
  float s2 = v[0]*v[0] + v[1]*v[1] + v[2]*v[2] + v[3]*v[3];
#pragma unroll
  for (int m = 32; m >= 1; m >>= 1) { s += __shfl_xor(s, m); s2 += __shfl_xor(s2, m); }
  const int w = t >> 6;
  if ((t & 63) == 0) { red[w] = s; red[4 + w] = s2; }
  __syncthreads();
  s  = red[0] + red[1] + red[2] + red[3];
  s2 = red[4] + red[5] + red[6] + red[7];
  const float mean = s * (1.f / 1024.f);
  const float var  = s2 * (1.f / 1024.f) - mean * mean;
  const float rstd = rsqrtf(var + 1e-5f);
  us4 o;
#pragma unroll
  for (int j = 0; j < 4; ++j) {
    const float zv = (v[j] - mean) * rstd;
    o[j] = f2bf(AFFINE ? zv * g[t * 4 + j] + bb[t * 4 + j] : zv);
  }
  *(us4*)(y + base + t * 4) = o;
}

// ---------------- GEMM core (R9-verified): 128x128 tile, 2-phase dbuf ----------------
template <int MODE, int BK>
DEV void gemm_core(const unsigned short* __restrict__ A,
                   const unsigned short* __restrict__ Bt,
                   const float* __restrict__ bias,
                   void* __restrict__ Cout,
                   const float* __restrict__ res,
                   int N, int K, int bx, int by,
                   unsigned short* sA, unsigned short* sB) {
  const int t = threadIdx.x;
  const int l = t & 63, w = t >> 6;
  const int wr = w >> 1, wc = w & 1;

  constexpr int  LPR = BK / 8;
  constexpr int  RPI = 64 / LPR;
  constexpr int  IPW = 32 / RPI;
  constexpr int  BUF = 128 * BK;
  constexpr bool SWZ = (BK == 64);

  const int glr = l / LPR;
  const int glc = SWZ ? (((l & 7) ^ (l >> 3)) << 3) : ((l % LPR) << 3);
  const unsigned short* gA = A  + (size_t)(by * 128 + w * 32 + glr) * K + glc;
  const unsigned short* gB = Bt + (size_t)(bx * 128 + w * 32 + glr) * K + glc;
  const int wofs = w * 32 * BK;

  const int lr = l & 15;
  const int gq = l >> 4;
  const int xr = SWZ ? (lr & 7) : 0;

  f32x4 acc[4][4];
#pragma unroll
  for (int m = 0; m < 4; ++m)
#pragma unroll
    for (int n = 0; n < 4; ++n) { acc[m][n][0]=0.f; acc[m][n][1]=0.f; acc[m][n][2]=0.f; acc[m][n][3]=0.f; }

  auto stage = [&](int buf, int k0) {
#pragma unroll
    for (int i = 0; i < IPW; ++i) {
      gll16(gA + (size_t)i * RPI * K + k0, sA + buf * BUF + wofs + i * RPI * BK);
      gll16(gB + (size_t)i * RPI * K + k0, sB + buf * BUF + wofs + i * RPI * BK);
    }
  };
  auto compute = [&](int buf) {
#pragma unroll
    for (int ks = 0; ks < BK / 32; ++ks) {
      const int col = (((ks * 4 + gq) ^ xr) << 3);
      const unsigned short* sAr = sA + buf * BUF + (wr * 64 + lr) * BK + col;
      const unsigned short* sBr = sB + buf * BUF + (wc * 64 + lr) * BK + col;
      bf16x8 af[4], bfr[4];
#pragma unroll
      for (int m = 0; m < 4; ++m) af[m]  = *(const bf16x8*)(sAr + m * 16 * BK);
#pragma unroll
      for (int n = 0; n < 4; ++n) bfr[n] = *(const bf16x8*)(sBr + n * 16 * BK);
#pragma unroll
      for (int m = 0; m < 4; ++m)
#pragma unroll
        for (int n = 0; n < 4; ++n)
          acc[m][n] = __builtin_amdgcn_mfma_f32_16x16x32_bf16(af[m], bfr[n], acc[m][n], 0, 0, 0);
    }
  };

  stage(0, 0);
  __syncthreads();
  int cur = 0;
  for (int k0 = BK; k0 < K; k0 += BK) {
    stage(cur ^ 1, k0);
    compute(cur);
    __syncthreads();
    cur ^= 1;
  }
  compute(cur);

  const int rq = (l >> 4) << 2;  // C/D: col = lane&15, row = (lane>>4)*4 + reg
#pragma unroll
  for (int n = 0; n < 4; ++n) {
    const int cg = bx * 128 + wc * 64 + n * 16 + lr;
    const float bv = bias[cg];
#pragma unroll
    for (int m = 0; m < 4; ++m) {
#pragma unroll
      for (int r = 0; r < 4; ++r) {
        const int rg = by * 128 + wr * 64 + m * 16 + rq + r;
        const float v = acc[m][n][r] + bv;
        if constexpr (MODE == 0) {
          ((unsigned short*)Cout)[(size_t)rg * N + cg] = f2bf(v);
        } else if constexpr (MODE == 1) {
          ((unsigned short*)Cout)[(size_t)rg * N + cg] = f2bf(v > 0.f ? v : 0.f);
        } else {
          ((float*)Cout)[(size_t)rg * N + cg] = res[(size_t)rg * N + cg] + v;
        }
      }
    }
  }
}

template <int MODE, int BK>
__global__ __launch_bounds__(256)
void k_gemm(const unsigned short* __restrict__ A,
            const unsigned short* __restrict__ Bt,
            const float* __restrict__ bias,
            void* __restrict__ Cout,
            const float* __restrict__ res,
            int N, int K, int nbx) {
  __shared__ unsigned short sA[2 * 128 * BK];
  __shared__ unsigned short sB[2 * 128 * BK];
  const int nwg = gridDim.x;
  const int q8  = nwg >> 3;
  const int swz = (blockIdx.x & 7) * q8 + (blockIdx.x >> 3);
  gemm_core<MODE, BK>(A, Bt, bias, Cout, res, N, K, swz % nbx, swz / nbx, sA, sB);
}

// ---------------- 8-wave 128x128 BK=64 GEMM (R15-verified): 16 waves/CU ----------------
// MODE 2: f32 res -> bf16 out; MODE 3: bf16 res -> f32 out.
template <int MODE>
__global__ __launch_bounds__(512)
void k_gemm8(const unsigned short* __restrict__ A,
             const unsigned short* __restrict__ Bt,
             const float* __restrict__ bias,
             void* __restrict__ Cout,
             const void* __restrict__ res,
             int N, int K, int nbx) {
  constexpr int BUF = 128 * 64;
  __shared__ unsigned short sA[2 * BUF];
  __shared__ unsigned short sB[2 * BUF];
  const int t = threadIdx.x, l = t & 63, w = t >> 6;
  const int wr = w >> 1, wc = w & 1;
  const int nwg = gridDim.x, q8 = nwg >> 3;
  const int swz = (blockIdx.x & 7) * q8 + (blockIdx.x >> 3);
  const int bx = swz % nbx, by = swz / nbx;

  const int srow = w * 8 + (l >> 3);
  const int scol = ((l & 7) ^ ((l >> 3) & 7)) << 3;
  const unsigned short* gA = A  + (size_t)(by * 128 + srow) * K + scol;
  const unsigned short* gB = Bt + (size_t)(bx * 128 + srow) * K + scol;
  const size_t r64 = (size_t)64 * K;
  const int wofs = w * 8 * 64;

  const int lr = l & 15, gq = l >> 4, xr = lr & 7;

  f32x4 acc[2][4];
#pragma unroll
  for (int m = 0; m < 2; ++m)
#pragma unroll
    for (int n = 0; n < 4; ++n) { acc[m][n][0]=0.f; acc[m][n][1]=0.f; acc[m][n][2]=0.f; acc[m][n][3]=0.f; }

  auto stage = [&](int buf, int k0) {
    gll16(gA + k0,       sA + buf * BUF + wofs);
    gll16(gA + r64 + k0, sA + buf * BUF + wofs + 64 * 64);
    gll16(gB + k0,       sB + buf * BUF + wofs);
    gll16(gB + r64 + k0, sB + buf * BUF + wofs + 64 * 64);
  };
  auto compute = [&](int buf) {
#pragma unroll
    for (int ks = 0; ks < 2; ++ks) {
      const int col = (((ks * 4 + gq) ^ xr) << 3);
      const unsigned short* sAr = sA + buf * BUF + (wr * 32 + lr) * 64 + col;
      const unsigned short* sBr = sB + buf * BUF + (wc * 64 + lr) * 64 + col;
      bf16x8 af[2], bfr[4];
#pragma unroll
      for (int m = 0; m < 2; ++m) af[m]  = *(const bf16x8*)(sAr + m * 16 * 64);
#pragma unroll
      for (int n = 0; n < 4; ++n) bfr[n] = *(const bf16x8*)(sBr + n * 16 * 64);
#pragma unroll
      for (int m = 0; m < 2; ++m)
#pragma unroll
        for (int n = 0; n < 4; ++n)
          acc[m][n] = __builtin_amdgcn_mfma_f32_16x16x32_bf16(af[m], bfr[n], acc[m][n], 0, 0, 0);
    }
  };

  stage(0, 0);
  __syncthreads();
  int cur = 0;
  for (int k0 = 64; k0 < K; k0 += 64) {
    stage(cur ^ 1, k0);
    compute(cur);
    __syncthreads();
    cur ^= 1;
  }
  compute(cur);

  const int rq = (l >> 4) << 2;
#pragma unroll
  for (int n = 0; n < 4; ++n) {
    const int cg = bx * 128 + wc * 64 + n * 16 + lr;
    const float bv = bias[cg];
#pragma unroll
    for (int m = 0; m < 2; ++m) {
#pragma unroll
      for (int r = 0; r < 4; ++r) {
        const int rg = by * 128 + wr * 32 + m * 16 + rq + r;
        const size_t idx = (size_t)rg * N + cg;
        const float v = acc[m][n][r] + bv;
        if constexpr (MODE == 2) {
          ((unsigned short*)Cout)[idx] = f2bf(((const float*)res)[idx] + v);
        } else {
          ((float*)Cout)[idx] =
              bf2f((short)((const unsigned short*)res)[idx]) + v;
        }
      }
    }
  }
}

// ---------------- WIDE GEMM core (R16-verified): 256x128, 8 waves, slot-swizzled ------
template <int MODE>
DEV void gemm_w_core(const unsigned short* __restrict__ A,
                     const unsigned short* __restrict__ Bt,
                     const float* __restrict__ bias,
                     unsigned short* __restrict__ Cout,
                     int N, int K, int bx, int by,
                     unsigned short* sA, unsigned short* sB) {
  constexpr int BUFA = 256 * 32;
  constexpr int BUFB = 128 * 32;
  const int t = threadIdx.x, l = t & 63, w = t >> 6;
  const int wr = w >> 1, wc = w & 1;

  const int glr = l >> 2;
  const int glc = ((l & 3) ^ ((l >> 3) & 3)) << 3;
  const unsigned short* gA = A  + (size_t)(by * 256 + w * 32 + glr) * K + glc;
  const unsigned short* gB = Bt + (size_t)(bx * 128 + w * 16 + glr) * K + glc;
  const size_t r16 = (size_t)16 * K;
  const int wofsA = w * 32 * 32;
  const int wofsB = w * 16 * 32;

  const int lr = l & 15;
  const int lk = (((l >> 4) ^ ((l >> 1) & 3)) << 3);

  f32x4 acc[4][4];
#pragma unroll
  for (int m = 0; m < 4; ++m)
#pragma unroll
    for (int n = 0; n < 4; ++n) { acc[m][n][0]=0.f; acc[m][n][1]=0.f; acc[m][n][2]=0.f; acc[m][n][3]=0.f; }

  auto stage = [&](int buf, int k0) {
    gll16(gA + k0,       sA + buf * BUFA + wofsA);
    gll16(gA + r16 + k0, sA + buf * BUFA + wofsA + 512);
    gll16(gB + k0,       sB + buf * BUFB + wofsB);
  };
  auto compute = [&](int buf) {
    const unsigned short* sAr = sA + buf * BUFA + (wr * 64 + lr) * 32 + lk;
    const unsigned short* sBr = sB + buf * BUFB + (wc * 64 + lr) * 32 + lk;
    bf16x8 af[4], bfr[4];
#pragma unroll
    for (int m = 0; m < 4; ++m) af[m]  = *(const bf16x8*)(sAr + m * 16 * 32);
#pragma unroll
    for (int n = 0; n < 4; ++n) bfr[n] = *(const bf16x8*)(sBr + n * 16 * 32);
#pragma unroll
    for (int m = 0; m < 4; ++m)
#pragma unroll
      for (int n = 0; n < 4; ++n)
        acc[m][n] = __builtin_amdgcn_mfma_f32_16x16x32_bf16(af[m], bfr[n], acc[m][n], 0, 0, 0);
  };

  stage(0, 0);
  __syncthreads();
  int cur = 0;
  for (int k0 = 32; k0 < K; k0 += 32) {
    stage(cur ^ 1, k0);
    compute(cur);
    __syncthreads();
    cur ^= 1;
  }
  compute(cur);

  const int rq = (l >> 4) << 2;
#pragma unroll
  for (int n = 0; n < 4; ++n) {
    const int cg = bx * 128 + wc * 64 + n * 16 + lr;
    const float bv = bias[cg];
#pragma unroll
    for (int m = 0; m < 4; ++m) {
#pragma unroll
      for (int r = 0; r < 4; ++r) {
        const int rg = by * 256 + wr * 64 + m * 16 + rq + r;
        const float v = acc[m][n][r] + bv;
        if constexpr (MODE == 0) {
          Cout[(size_t)rg * N + cg] = f2bf(v);
        } else {
          Cout[(size_t)rg * N + cg] = f2bf(v > 0.f ? v : 0.f);
        }
      }
    }
  }
}

template <int MODE>
__global__ __launch_bounds__(512)
void k_gemm_w(const unsigned short* __restrict__ A,
              const unsigned short* __restrict__ Bt,
              const float* __restrict__ bias,
              unsigned short* __restrict__ Cout,
              int N, int K, int nbx) {
  __shared__ unsigned short sA[2 * 256 * 32];
  __shared__ unsigned short sB[2 * 128 * 32];
  const int nwg = gridDim.x, q8 = nwg >> 3;
  const int swz = (blockIdx.x & 7) * q8 + (blockIdx.x >> 3);
  gemm_w_core<MODE>(A, Bt, bias, Cout, N, K, swz % nbx, swz / nbx, sA, sB);
}

__global__ __launch_bounds__(512)
void k_gemm2_w(const unsigned short* __restrict__ A0, const unsigned short* __restrict__ B0,
               const float* __restrict__ b0, unsigned short* __restrict__ C0,
               const unsigned short* __restrict__ A1, const unsigned short* __restrict__ B1,
               const float* __restrict__ b1, unsigned short* __restrict__ C1,
               int N, int K, int nbx, int nblk0) {
  __shared__ unsigned short sA[2 * 256 * 32];
  __shared__ unsigned short sB[2 * 128 * 32];
  const int nwg = gridDim.x, q8 = nwg >> 3;
  int swz = (blockIdx.x & 7) * q8 + (blockIdx.x >> 3);
  const unsigned short* A; const unsigned short* Bt; const float* bias; unsigned short* C;
  if (swz < nblk0) { A = A0; Bt = B0; bias = b0; C = C0; }
  else { swz -= nblk0; A = A1; Bt = B1; bias = b1; C = C1; }
  gemm_w_core<0>(A, Bt, bias, C, N, K, swz % nbx, swz / nbx, sA, sB);
}

__global__ __launch_bounds__(512)
void k_gemm3_w(const unsigned short* __restrict__ A0, const unsigned short* __restrict__ B0,
               const float* __restrict__ b0, unsigned short* __restrict__ C0,
               const unsigned short* __restrict__ A1, const unsigned short* __restrict__ B1,
               const float* __restrict__ b1, unsigned short* __restrict__ C1,
               const unsigned short* __restrict__ A2, const unsigned short* __restrict__ B2,
               const float* __restrict__ b2, unsigned short* __restrict__ C2,
               int N, int K, int nbx, int nblk0, int nblk1) {
  __shared__ unsigned short sA[2 * 256 * 32];
  __shared__ unsigned short sB[2 * 128 * 32];
  const int nwg = gridDim.x, q8 = nwg >> 3;
  int swz = (blockIdx.x & 7) * q8 + (blockIdx.x >> 3);
  const unsigned short* A; const unsigned short* Bt; const float* bias; unsigned short* C;
  if (swz < nblk0) { A = A0; Bt = B0; bias = b0; C = C0; }
  else if (swz < nblk0 + nblk1) { swz -= nblk0; A = A1; Bt = B1; bias = b1; C = C1; }
  else { swz -= nblk0 + nblk1; A = A2; Bt = B2; bias = b2; C = C2; }
  gemm_w_core<0>(A, Bt, bias, C, N, K, swz % nbx, swz / nbx, sA, sB);
}

// 3-group 128^2 GEMM (tier-1 visual fallback)
__global__ __launch_bounds__(256)
void k_gemm3(const unsigned short* __restrict__ A0, const unsigned short* __restrict__ B0,
             const float* __restrict__ b0, unsigned short* __restrict__ C0,
             const unsigned short* __restrict__ A1, const unsigned short* __restrict__ B1,
             const float* __restrict__ b1, unsigned short* __restrict__ C1,
             const unsigned short* __restrict__ A2, const unsigned short* __restrict__ B2,
             const float* __restrict__ b2, unsigned short* __restrict__ C2,
             int N, int K, int nbx, int nblk0, int nblk1) {
  __shared__ unsigned short sA[2 * 128 * 32];
  __shared__ unsigned short sB[2 * 128 * 32];
  const int nwg = gridDim.x;
  const int q8  = nwg >> 3;
  int swz = (blockIdx.x & 7) * q8 + (blockIdx.x >> 3);
  const unsigned short* A; const unsigned short* Bt; const float* bias; unsigned short* C;
  if (swz < nblk0) { A = A0; Bt = B0; bias = b0; C = C0; }
  else if (swz < nblk0 + nblk1) { swz -= nblk0; A = A1; Bt = B1; bias = b1; C = C1; }
  else { swz -= nblk0 + nblk1; A = A2; Bt = B2; bias = b2; C = C2; }
  gemm_core<0, 32>(A, Bt, bias, C, nullptr, N, K, swz % nbx, swz / nbx, sA, sB);
}

// ---------------- MFMA flash attention (R14-verified + R18 setprio) ----------------
template <bool CAUSAL>
__global__ __launch_bounds__(512)
void k_attn_mfma(const unsigned short* __restrict__ Q,
                 const unsigned short* __restrict__ Kb,
                 const unsigned short* __restrict__ Vb,
                 unsigned short* __restrict__ O,
                 int kvlen, int qs, int ks) {
  __shared__ __align__(16) unsigned short sK [64 * 64];
  __shared__ __align__(16) unsigned short sVt[64 * 64];
  __shared__ __align__(16) unsigned short sP [8][16 * 64];
  const int b = blockIdx.z, h = blockIdx.y, q0 = blockIdx.x * 128;
  const int t = threadIdx.x, w = t >> 6, l = t & 63;
  const int cc = l & 15, g = l >> 4;
  const int gk = g << 3;

  const unsigned short* qg =
      Q + (size_t)(b * 512 + q0 + w * 16 + cc) * qs + h * 64 + gk;
  bf16x8 qf[2];
  qf[0] = *(const bf16x8*)(qg);
  qf[1] = *(const bf16x8*)(qg + 32);

  f32x4 accO[4];
#pragma unroll
  for (int n = 0; n < 4; ++n) { accO[n][0]=0.f; accO[n][1]=0.f; accO[n][2]=0.f; accO[n][3]=0.f; }
  float om[4], ls[4];
#pragma unroll
  for (int r = 0; r < 4; ++r) { om[r] = -1e30f; ls[r] = 0.f; }

  const int krow = w * 8 + (l >> 3);
  const int kcol = ((l & 7) ^ ((l >> 3) & 7)) << 3;
  const size_t kstg = (size_t)(b * kvlen + krow) * ks + h * 64 + kcol;
  unsigned short* kdst = sK + w * 8 * 64;

  const int vrow = t >> 3;
  const int vd0  = (t & 7) << 3;
  const size_t vstg = (size_t)(b * kvlen + vrow) * ks + h * 64 + vd0;

  const int kvmax = CAUSAL ? (q0 + 128) : kvlen;
  for (int c0 = 0; c0 < kvmax; c0 += 64) {
    __syncthreads();
    gll16(Kb + kstg + (size_t)c0 * ks, kdst);
    const bf16x8 vv = *(const bf16x8*)(Vb + vstg + (size_t)c0 * ks);
#pragma unroll
    for (int i = 0; i < 8; ++i) {
      const int j = (i + (t & 7)) & 7;
      sVt[(vd0 + j) * 64 + (vrow ^ (j << 3))] = (unsigned short)vv[j];
    }
    __syncthreads();

    // ---- S = Q.K^T (T5: setprio around MFMA cluster) ----
    f32x4 S[4];
#pragma unroll
    for (int n = 0; n < 4; ++n) { S[n][0]=0.f; S[n][1]=0.f; S[n][2]=0.f; S[n][3]=0.f; }
    __builtin_amdgcn_s_setprio(1);
#pragma unroll
    for (int n = 0; n < 4; ++n) {
      const int kvr = (n * 16 + cc) * 64;
      const int sxk = (cc & 7) << 3;
#pragma unroll
      for (int ks2 = 0; ks2 < 2; ++ks2) {
        const bf16x8 kf = *(const bf16x8*)(sK + kvr + ((ks2 * 32 + gk) ^ sxk));
        S[n] = __builtin_amdgcn_mfma_f32_16x16x32_bf16(qf[ks2], kf, S[n], 0, 0, 0);
      }
    }
    __builtin_amdgcn_s_setprio(0);

    float cm[4];
#pragma unroll
    for (int r = 0; r < 4; ++r) cm[r] = -1e30f;
#pragma unroll
    for (int n = 0; n < 4; ++n) {
      const int kvg = c0 + n * 16 + cc;
#pragma unroll
      for (int r = 0; r < 4; ++r) {
        const int qrow = q0 + w * 16 + g * 4 + r;
        const bool valid = (kvg < kvlen) && (!CAUSAL || kvg <= qrow);
        const float sv = valid ? S[n][r] * 0.125f : -1e30f;
        S[n][r] = sv;
        cm[r] = fmaxf(cm[r], sv);
      }
    }
#pragma unroll
    for (int m2 = 1; m2 <= 8; m2 <<= 1)
#pragma unroll
      for (int r = 0; r < 4; ++r) cm[r] = fmaxf(cm[r], __shfl_xor(cm[r], m2));

    float sc4[4], ps[4];
#pragma unroll
    for (int r = 0; r < 4; ++r) {
      const float mn = fmaxf(om[r], cm[r]);
      sc4[r] = __expf(om[r] - mn);
      om[r] = mn;
      ps[r] = 0.f;
    }
#pragma unroll
    for (int n = 0; n < 4; ++n) {
#pragma unroll
      for (int r = 0; r < 4; ++r) {
        const float pv = __expf(S[n][r] - om[r]);
        ps[r] += pv;
        const int q = g * 4 + r;
        sP[w][q * 64 + ((n * 16 + cc) ^ ((q & 7) << 3))] = f2bf(pv);
      }
    }
#pragma unroll
    for (int m2 = 1; m2 <= 8; m2 <<= 1)
#pragma unroll
      for (int r = 0; r < 4; ++r) ps[r] += __shfl_xor(ps[r], m2);
#pragma unroll
    for (int r = 0; r < 4; ++r) ls[r] = ls[r] * sc4[r] + ps[r];
#pragma unroll
    for (int n = 0; n < 4; ++n)
#pragma unroll
      for (int r = 0; r < 4; ++r) accO[n][r] *= sc4[r];

    // ---- O += P.V (T5: setprio around MFMA cluster) ----
    const int pxk = (cc & 7) << 3;
    __builtin_amdgcn_s_setprio(1);
#pragma unroll
    for (int ks2 = 0; ks2 < 2; ++ks2) {
      const bf16x8 pf = *(const bf16x8*)(&sP[w][cc * 64 + ((ks2 * 32 + gk) ^ pxk)]);
#pragma unroll
      for (int n = 0; n < 4; ++n) {
        const int d = n * 16 + cc;
        const bf16x8 vf = *(const bf16x8*)(sVt + d * 64 + ((ks2 * 32 + gk) ^ ((d & 7) << 3)));
        accO[n] = __builtin_amdgcn_mfma_f32_16x16x32_bf16(pf, vf, accO[n], 0, 0, 0);
      }
    }
    __builtin_amdgcn_s_setprio(0);
  }

#pragma unroll
  for (int r = 0; r < 4; ++r) {
    const float inv = 1.f / ls[r];
    const size_t ob = ((size_t)(b * 512 + q0 + w * 16 + g * 4 + r) << 10) + h * 64;
#pragma unroll
    for (int n = 0; n < 4; ++n)
      O[ob + n * 16 + cc] = f2bf(accO[n][r] * inv);
  }
}

// ---------------- fuse gate, phase 1 (c is bf16) ----------------
__global__ __launch_bounds__(256)
void k_pair1(const unsigned short* __restrict__ c, const unsigned short* __restrict__ p1,
             const unsigned short* __restrict__ p2, unsigned short* __restrict__ acc) {
  __shared__ float red[8];
  const size_t base = (size_t)blockIdx.x * 1024;
  const int t = threadIdx.x;
  const us4 uc = *(const us4*)(c + base + t * 4);
  const us4 u1 = *(const us4*)(p1 + base + t * 4);
  const us4 u2 = *(const us4*)(p2 + base + t * 4);
  float cv[4], f1v[4], f2v[4];
  float d1 = 0.f, d2 = 0.f;
#pragma unroll
  for (int j = 0; j < 4; ++j) {
    cv[j] = bf2f((short)uc[j]);
    f1v[j] = bf2f((short)u1[j]); f2v[j] = bf2f((short)u2[j]);
    d1 += cv[j] * f1v[j]; d2 += cv[j] * f2v[j];
  }
#pragma unroll
  for (int m = 32; m >= 1; m >>= 1) { d1 += __shfl_xor(d1, m); d2 += __shfl_xor(d2, m); }
  const int w = t >> 6;
  if ((t & 63) == 0) { red[w] = d1; red[4 + w] = d2; }
  __syncthreads();
  d1 = red[0] + red[1] + red[2] + red[3];
  d2 = red[4] + red[5] + red[6] + red[7];
  const float mx = fmaxf(d1, d2);
  const float e1 = __expf(d1 - mx), e2 = __expf(d2 - mx);
  const float w1 = e1 / (e1 + e2), w2 = e2 / (e1 + e2);
  us4 o;
#pragma unroll
  for (int j = 0; j < 4; ++j) o[j] = f2bf(0.5f * (w1 * f1v[j] + w2 * f2v[j]));
  *(us4*)(acc + base + t * 4) = o;
}

// ---------------- fuse gate phase 2 + final LayerNorm (c is bf16, in/out) --------------
__global__ __launch_bounds__(256)
void k_pair2ln(unsigned short* __restrict__ c, const unsigned short* __restrict__ p1,
               const unsigned short* __restrict__ p2, const unsigned short* __restrict__ acc,
               const float* __restrict__ g, const float* __restrict__ bb,
               unsigned short* __restrict__ y) {
  __shared__ float red[16];
  const size_t base = (size_t)blockIdx.x * 1024;
  const int t = threadIdx.x;
  const int w = t >> 6;
  const us4 uc = *(const us4*)(c + base + t * 4);
  const us4 u1 = *(const us4*)(p1 + base + t * 4);
  const us4 u2 = *(const us4*)(p2 + base + t * 4);
  const us4 ua = *(const us4*)(acc + base + t * 4);
  float cv[4], f1v[4], f2v[4];
  float d1 = 0.f, d2 = 0.f;
#pragma unroll
  for (int j = 0; j < 4; ++j) {
    cv[j] = bf2f((short)uc[j]);
    f1v[j] = bf2f((short)u1[j]); f2v[j] = bf2f((short)u2[j]);
    d1 += cv[j] * f1v[j]; d2 += cv[j] * f2v[j];
  }
#pragma unroll
  for (int m = 32; m >= 1; m >>= 1) { d1 += __shfl_xor(d1, m); d2 += __shfl_xor(d2, m); }
  if ((t & 63) == 0) { red[w] = d1; red[4 + w] = d2; }
  __syncthreads();
  d1 = red[0] + red[1] + red[2] + red[3];
  d2 = red[4] + red[5] + red[6] + red[7];
  const float mx = fmaxf(d1, d2);
  const float e1 = __expf(d1 - mx), e2 = __expf(d2 - mx);
  const float w1 = e1 / (e1 + e2), w2 = e2 / (e1 + e2);
  f32x4 o;
  us4 oc;
  float s = 0.f, s2 = 0.f;
#pragma unroll
  for (int j = 0; j < 4; ++j) {
    o[j] = cv[j] + bf2f((short)ua[j]) + 0.5f * (w1 * f1v[j] + w2 * f2v[j]);
    oc[j] = f2bf(o[j]);
    s += o[j]; s2 += o[j] * o[j];
  }
  *(us4*)(c + base + t * 4) = oc;
#pragma unroll
  for (int m = 32; m >= 1; m >>= 1) { s += __shfl_xor(s, m); s2 += __shfl_xor(s2, m); }
  if ((t & 63) == 0) { red[8 + w] = s; red[12 + w] = s2; }
  __syncthreads();
  s  = red[8]  + red[9]  + red[10] + red[11];
  s2 = red[12] + red[13] + red[14] + red[15];
  const float mean = s * (1.f / 1024.f);
  const float var  = s2 * (1.f / 1024.f) - mean * mean;
  const float rstd = rsqrtf(var + 1e-5f);
  us4 yo;
#pragma unroll
  for (int j = 0; j < 4; ++j)
    yo[j] = f2bf((o[j] - mean) * rstd * g[t * 4 + j] + bb[t * 4 + j]);
  *(us4*)(y + base + t * 4) = yo;
}

// ---------------- host ----------------
extern "C" void kernel_launch(void* const* d_in, const int* in_sizes, int n_in,
                              void* d_out, int out_size, void* d_ws, size_t ws_size,
                              hipStream_t stream) {
  (void)in_sizes; (void)n_in; (void)out_size;
  const float* captions      = (const float*)d_in[0];
  const float* cpt_words     = (const float*)d_in[1];
  const float* senti_words   = (const float*)d_in[2];
  const float* region_feats  = (const float*)d_in[3];
  const float* spatial_feats = (const float*)d_in[4];
  const float* att_W  = (const float*)d_in[5];
  const float* att_b  = (const float*)d_in[6];
  const float* ffn_W1 = (const float*)d_in[7];
  const float* ffn_b1 = (const float*)d_in[8];
  const float* ffn_W2 = (const float*)d_in[9];
  const float* ffn_b2 = (const float*)d_in[10];
  const float* ln_g   = (const float*)d_in[11];
  const float* ln_b   = (const float*)d_in[12];
  // d_in[13] seq_masks: tril by construction -> causal handled analytically.

  const bool m2 = ws_size >= (size_t)193500000;
  const bool m1 = m2 || ws_size >= (size_t)191000000;
  const int  RPV = m2 ? 3328 : 3200;

  char* ws = (char*)d_ws;
  size_t off = 0;
  auto alloc = [&](size_t bytes) {
    char* p = ws + off;
    off += (bytes + 255) & ~(size_t)255;
    return p;
  };
  const size_t M8 = (size_t)8 * 1024 * 1024;
  unsigned short* hbuf = (unsigned short*)alloc(M8 * 2);
  unsigned short* qx   = (unsigned short*)alloc(M8 * 2 * 4);
  unsigned short* c1   = (unsigned short*)alloc(M8 * 2);   // residual, bf16
  unsigned short* uni  = (unsigned short*)alloc(M8 * 2);
  unsigned short* wbuf = (unsigned short*)alloc(M8 * 2);
  unsigned short* padbA = (unsigned short*)alloc((size_t)RPV * 1024 * 2);
  unsigned short* padbB = m1 ? (unsigned short*)alloc((size_t)RPV * 1024 * 2) : padbA;
  unsigned short* kvbA  = (unsigned short*)alloc((size_t)RPV * 2048 * 2);
  unsigned short* kvbB  = m1 ? (unsigned short*)alloc((size_t)RPV * 2048 * 2) : kvbA;
  float*          qbs  = (float*)alloc(2048 * 4);

  const long long MSL = 1048576;
  const size_t    MSE = 1048576;
  unsigned short* accb = uni;
  unsigned short* wF1t = uni;
  unsigned short* wF2t = uni + (size_t)4096 * 1024;

  const dim3 tb32(32, 8);
  const dim3 gAttn(4, 16, 16);       // QBLK=128

  // ================= self attention (causal) =================
  k_transpose_cvt<<<dim3(32, 32, 4), tb32, 0, stream>>>(att_W, wbuf, 2 * MSL, MSL,
                                                        nullptr, 0, 1024, 1024);
  k_ln<true, false><<<8192, 256, 0, stream>>>(captions, ln_g, ln_b, hbuf);
  k_gemm_w<0><<<768, 512, 0, stream>>>(hbuf, wbuf, att_b, qx, 3072, 1024, 24);
  k_attn_mfma<true><<<gAttn, 512, 0, stream>>>(qx, qx + 1024, qx + 2048,
                                               qx + 3 * M8, 512, 3072, 3072);
  k_gemm8<2><<<512, 512, 0, stream>>>(qx + 3 * M8, wbuf + 3 * MSE, att_b + 3 * 1024,
                                      c1, captions, 1024, 1024, 8);

  // ================= branches (paired), folded LN =================
  k_ln<false, true><<<8192, 256, 0, stream>>>(c1, nullptr, nullptr, hbuf);

  auto branch_pair = [&](int bi0, int Rp, int valid, bool wideKV,
                         const float* wrd0, const float* wrd1, int phase) {
    k_transpose_pair<<<dim3(32, 32, 8), tb32, 0, stream>>>(
        att_W + (size_t)bi0 * 4 * MSE, wbuf, ln_g + (size_t)bi0 * 1024);
    k_foldbias2<<<32, 256, 0, stream>>>(ln_b + (size_t)bi0 * 1024,
                                        att_W + (size_t)bi0 * 4 * MSE,
                                        att_b + (size_t)bi0 * 4 * 1024, qbs);
    const int nrows = valid * 16;
    const float* bKa = att_b + ((size_t)bi0 * 4 + 1) * 1024;
    const float* bKb = att_b + ((size_t)(bi0 + 1) * 4 + 1) * 1024;

    if (m1) {
      k_cvt_pad2<<<dim3(Rp, 2), 256, 0, stream>>>(wrd0, wrd1, padbA, padbB, nrows);
      if (wideKV) {
        const int kvw = (Rp / 256) * 16;
        k_gemm3_w<<<512 + 2 * kvw, 512, 0, stream>>>(
            hbuf, wbuf, qbs, qx,
            padbA, wbuf + 2 * MSE, bKa, kvbA,
            padbB, wbuf + 4 * MSE, bKb, kvbB,
            2048, 1024, 16, 512, kvw);
      } else {
        const int kvblk = (Rp / 128) * 16;
        k_gemm3<<<1024 + 2 * kvblk, 256, 0, stream>>>(
            hbuf, wbuf, qbs, qx,
            padbA, wbuf + 2 * MSE, bKa, kvbA,
            padbB, wbuf + 4 * MSE, bKb, kvbB,
            2048, 1024, 16, 1024, kvblk);
      }
      k_attn_mfma<false><<<gAttn, 512, 0, stream>>>(
          qx, kvbA, kvbA + 1024, qx + 2 * M8, valid, 2048, 2048);
      k_attn_mfma<false><<<gAttn, 512, 0, stream>>>(
          qx + 1024, kvbB, kvbB + 1024, qx + 3 * M8, valid, 2048, 2048);
    } else {
      const int kvblk = (Rp / 128) * 16;
      k_gemm<0, 32><<<1024, 256, 0, stream>>>(hbuf, wbuf, qbs, qx, nullptr,
                                              2048, 1024, 16);
      k_cvt_pad<<<Rp, 256, 0, stream>>>(wrd0, padbA, nrows);
      k_gemm<0, 32><<<kvblk, 256, 0, stream>>>(padbA, wbuf + 2 * MSE, bKa,
                                               kvbA, nullptr, 2048, 1024, 16);
      k_attn_mfma<false><<<gAttn, 512, 0, stream>>>(
          qx, kvbA, kvbA + 1024, qx + 2 * M8, valid, 2048, 2048);
      k_cvt_pad<<<Rp, 256, 0, stream>>>(wrd1, padbA, nrows);
      k_gemm<0, 32><<<kvblk, 256, 0, stream>>>(padbA, wbuf + 4 * MSE, bKb,
                                               kvbA, nullptr, 2048, 1024, 16);
      k_attn_mfma<false><<<gAttn, 512, 0, stream>>>(
          qx + 1024, kvbA, kvbA + 1024, qx + 3 * M8, valid, 2048, 2048);
    }
    k_gemm2_w<<<512, 512, 0, stream>>>(
        qx + 2 * M8, wbuf + 6 * MSE, att_b + ((size_t)bi0 * 4 + 3) * 1024, qx,
        qx + 3 * M8, wbuf + 7 * MSE, att_b + ((size_t)(bi0 + 1) * 4 + 3) * 1024,
        qx + M8, 1024, 1024, 8, 256);
    if (phase == 1) {
      k_pair1<<<8192, 256, 0, stream>>>(c1, qx, qx + M8, accb);
    } else {
      k_pair2ln<<<8192, 256, 0, stream>>>(c1, qx, qx + M8, accb,
                                          ln_g + 5 * 1024, ln_b + 5 * 1024, hbuf);
    }
  };

  branch_pair(1, 512, 25,  m1, cpt_words,    senti_words,   1);  // semantic
  branch_pair(3, RPV, 196, m2, region_feats, spatial_feats, 2);  // visual

  // ================= FFN (LN fused into k_pair2ln) =================
  k_transpose_cvt<<<dim3(128, 32, 1), tb32, 0, stream>>>(ffn_W1, wF1t, 0, 0,
                                                         nullptr, 0, 1024, 4096);
  k_transpose_cvt<<<dim3(32, 128, 1), tb32, 0, stream>>>(ffn_W2, wF2t, 0, 0,
                                                         nullptr, 0, 4096, 1024);
  k_gemm_w<1><<<1024, 512, 0, stream>>>(hbuf, wF1t, ffn_b1, qx, 4096, 1024, 32);
  k_gemm8<3><<<512, 512, 0, stream>>>(qx, wF2t, ffn_b2, (float*)d_out, c1,
                                      1024, 4096, 8);
}